// Round 2
// baseline (741.228 us; speedup 1.0000x reference)
//
#include <hip/hip_runtime.h>
#include <hip/hip_bf16.h>
#include <stdint.h>

#define IN_CH 64
#define OUT_CH 128

typedef __bf16 bf16x8 __attribute__((ext_vector_type(8)));
typedef float  f32x4  __attribute__((ext_vector_type(4)));

__device__ inline unsigned short f2bf(float f) {
    unsigned u = __float_as_uint(f);
    unsigned r = (u + 0x7fffu + ((u >> 16) & 1u)) >> 16;
    return (unsigned short)r;
}

// ---------- fast path ----------

// One prep kernel, three block-ranges:
//  [0, invBlocks)                : inv[] = zero_row; sums = 0
//  [invBlocks, invBlocks+cvtB)   : feats fp32 -> bf16 (+1 zero row)
//  [invBlocks+cvtB, ...)         : Wbt[k][c][i] = bf16(W[k][i][c])
__global__ void __launch_bounds__(256) prep_kernel(
    int* __restrict__ inv, int invTot, int zero_row, float* __restrict__ sums,
    const float4* __restrict__ f4, ushort* __restrict__ fb, int n4,
    const float* __restrict__ W, ushort* __restrict__ wbt,
    int invBlocks, int cvtBlocks)
{
    const int b = blockIdx.x;
    const int t = threadIdx.x;
    if (b < invBlocks) {
        int i = b * 256 + t;
        if (i < invTot) inv[i] = zero_row;
        if (b == 0) sums[t] = 0.f;
    } else if (b < invBlocks + cvtBlocks) {
        int i = (b - invBlocks) * 256 + t;
        if (i < n4 + 16) {
            ushort4 o;
            if (i < n4) {
                float4 v = f4[i];
                o.x = f2bf(v.x); o.y = f2bf(v.y); o.z = f2bf(v.z); o.w = f2bf(v.w);
            } else {
                o.x = 0; o.y = 0; o.z = 0; o.w = 0;   // zero row for absent entries
            }
            ((ushort4*)fb)[i] = o;
        }
    } else {
        int i = (b - invBlocks - cvtBlocks) * 256 + t;
        if (i < 9 * OUT_CH * IN_CH) {
            int ii = i & (IN_CH - 1);
            int c = (i >> 6) & (OUT_CH - 1);
            int k = i >> 13;
            wbt[i] = f2bf(W[((size_t)k * IN_CH + ii) * OUT_CH + c]);
        }
    }
}

// Inverse rulebook, atomic-free: for fixed k the in->out map of a strided
// conv is injective, so inv[out*9+k] has exactly one writer.
__global__ void __launch_bounds__(256) build_inv_kernel(
    const int* __restrict__ in_idx,
    const int* __restrict__ out_idx,
    const int* __restrict__ mask,
    int* __restrict__ inv,
    int R)
{
    int r = blockIdx.x * 256 + threadIdx.x;
    if (r >= R) return;
    int k = blockIdx.y;
    size_t e = (size_t)k * R + r;
    if (!mask[e]) return;
    inv[(size_t)out_idx[e] * 9 + k] = in_idx[e];
}

// Fused: out[e] = sum_k Wbt[k]^T . fb[inv[e][k]], + fused BN-stat partials.
// Wave = 16 entries x 128 channels. MFMA operand order is (W, F) so D is
// [ch][entry]: lane holds 4 CONSECUTIVE channels (quad*4+r) of entry col
// -> float4 stores. All 18 feature gathers are issued up front (one latency,
// ~72 VGPR) and pinned with sched_barrier; W-frags stream from L1/L2.
__global__ void __launch_bounds__(256, 3) fused_out_kernel(
    const ushort* __restrict__ fb,    // [N_in+1][64] bf16 (last row zeros)
    const ushort* __restrict__ wbt,   // [9][128][64] bf16
    const int* __restrict__ inv,      // [n_out][9]
    float* __restrict__ out,          // [n_out][128] fp32
    float* __restrict__ sums,         // [256]
    int n_out, int zero_row)
{
    const int lane = threadIdx.x & 63;
    const int w = threadIdx.x >> 6;
    const int col = lane & 15;
    const int quad = lane >> 4;
    const int entry = blockIdx.x * 64 + w * 16 + col;
    const bool ok = entry < n_out;

    // Per-lane inverse list (registers).
    int iv[9];
    {
        const int* __restrict__ p = inv + (size_t)(ok ? entry : 0) * 9;
#pragma unroll
        for (int k = 0; k < 9; ++k) iv[k] = ok ? p[k] : zero_row;
    }

    // Issue ALL feature gathers before any MFMA (18 loads in flight).
    bf16x8 F0[9], F1[9];
#pragma unroll
    for (int k = 0; k < 9; ++k) {
        const ushort* __restrict__ f = fb + (size_t)iv[k] * IN_CH + quad * 8;
        F0[k] = *(const bf16x8*)f;
        F1[k] = *(const bf16x8*)(f + 32);
    }
    __builtin_amdgcn_sched_barrier(0);

    f32x4 acc[8];
#pragma unroll
    for (int g = 0; g < 8; ++g) acc[g] = (f32x4){0.f, 0.f, 0.f, 0.f};

#pragma unroll
    for (int k = 0; k < 9; ++k) {
        const ushort* __restrict__ wk = wbt + (size_t)k * (OUT_CH * IN_CH);
#pragma unroll
        for (int g = 0; g < 8; ++g) {
            const ushort* __restrict__ p = wk + (size_t)(g * 16 + col) * IN_CH + quad * 8;
            bf16x8 W0 = *(const bf16x8*)p;
            bf16x8 W1 = *(const bf16x8*)(p + 32);
            acc[g] = __builtin_amdgcn_mfma_f32_16x16x32_bf16(W0, F0[k], acc[g], 0, 0, 0);
            acc[g] = __builtin_amdgcn_mfma_f32_16x16x32_bf16(W1, F1[k], acc[g], 0, 0, 0);
        }
    }

    // Store: lane holds channels g*16 + quad*4 + {0..3} of its entry.
    if (ok) {
        float* __restrict__ rp = out + (size_t)entry * OUT_CH + quad * 4;
#pragma unroll
        for (int g = 0; g < 8; ++g)
            *(f32x4*)(rp + g * 16) = acc[g];
    }

    // BN stats: sum over entries = butterfly over the 16 col-lanes
    // (xor masks 1,2,4,8 stay inside a quad). Invalid entries are exact
    // zeros (zero feature row), so they contribute nothing.
    f32x4 qq[8];
#pragma unroll
    for (int g = 0; g < 8; ++g) qq[g] = acc[g] * acc[g];
#pragma unroll
    for (int m = 1; m <= 8; m <<= 1) {
#pragma unroll
        for (int g = 0; g < 8; ++g) {
#pragma unroll
            for (int j = 0; j < 4; ++j) {
                acc[g][j] += __shfl_xor(acc[g][j], m);
                qq[g][j]  += __shfl_xor(qq[g][j], m);
            }
        }
    }

    __shared__ float redS[4][OUT_CH];
    __shared__ float redQ[4][OUT_CH];
    if (col == 0) {
#pragma unroll
        for (int g = 0; g < 8; ++g)
#pragma unroll
            for (int j = 0; j < 4; ++j) {
                redS[w][g * 16 + quad * 4 + j] = acc[g][j];
                redQ[w][g * 16 + quad * 4 + j] = qq[g][j];
            }
    }
    __syncthreads();
    if (threadIdx.x < OUT_CH) {
        int c = threadIdx.x;
        float a  = redS[0][c] + redS[1][c] + redS[2][c] + redS[3][c];
        float bq = redQ[0][c] + redQ[1][c] + redQ[2][c] + redQ[3][c];
        atomicAdd(&sums[c], a);
        atomicAdd(&sums[OUT_CH + c], bq);
    }
}

// y = gamma*(x-mean)*rsqrt(var+eps)+beta, relu; in-place, float4.
__global__ void __launch_bounds__(256) bn_relu_kernel(
    float4* __restrict__ out,
    const float* __restrict__ sums,
    const float* __restrict__ gamma,
    const float* __restrict__ beta,
    int total4, float inv_n)
{
    int idx = blockIdx.x * 256 + threadIdx.x;
    if (idx >= total4) return;
    int c0 = (idx & 31) * 4;
    float4 v = out[idx];
    float r[4] = {v.x, v.y, v.z, v.w};
#pragma unroll
    for (int j = 0; j < 4; ++j) {
        int c = c0 + j;
        float mean = sums[c] * inv_n;
        float var = sums[OUT_CH + c] * inv_n - mean * mean;
        float scale = gamma[c] * rsqrtf(var + 1e-5f);
        float y = (r[j] - mean) * scale + beta[c];
        r[j] = fmaxf(y, 0.0f);
    }
    out[idx] = make_float4(r[0], r[1], r[2], r[3]);
}

// ---------- fallback (atomic scatter) if ws too small ----------

__global__ void __launch_bounds__(256) zero_kernel(float4* __restrict__ out, int n4,
                                                   float* __restrict__ sums) {
    int idx = blockIdx.x * 256 + threadIdx.x;
    if (idx < n4) out[idx] = make_float4(0.f, 0.f, 0.f, 0.f);
    if (blockIdx.x == 0 && threadIdx.x < 2 * OUT_CH) sums[threadIdx.x] = 0.f;
}

__global__ void __launch_bounds__(256) scatter_gemm_kernel(
    const float* __restrict__ feats,
    const float* __restrict__ W,
    const int* __restrict__ in_idx,
    const int* __restrict__ out_idx,
    const int* __restrict__ mask,
    float* __restrict__ acc,
    int R)
{
    const int lane = threadIdx.x & 63;
    const int waveId = threadIdx.x >> 6;
    const int half = waveId & 1;
    const int pair = waveId >> 1;
    const int k = blockIdx.y;
    const int c = half * 64 + lane;

    float wreg[IN_CH];
    const float* __restrict__ wp = W + (size_t)k * IN_CH * OUT_CH + c;
#pragma unroll
    for (int i = 0; i < IN_CH; ++i) wreg[i] = wp[i * OUT_CH];

    const int r0 = blockIdx.x * 128;
    const int rEnd = min(r0 + 128, R);
    const int* __restrict__ maskK = mask + (size_t)k * R;
    const int* __restrict__ inK = in_idx + (size_t)k * R;
    const int* __restrict__ outK = out_idx + (size_t)k * R;

    for (int r = r0 + pair; r < rEnd; r += 2) {
        if (!__builtin_amdgcn_readfirstlane(maskK[r])) continue;
        int in = __builtin_amdgcn_readfirstlane(inK[r]);
        int out = __builtin_amdgcn_readfirstlane(outK[r]);
        const float* __restrict__ f = feats + (size_t)in * IN_CH;
        float s = 0.f, s1 = 0.f;
#pragma unroll
        for (int i = 0; i < IN_CH; i += 2) {
            s = fmaf(wreg[i], f[i], s);
            s1 = fmaf(wreg[i + 1], f[i + 1], s1);
        }
        atomicAdd(acc + (size_t)out * OUT_CH + c, s + s1);
    }
}

__global__ void __launch_bounds__(128) stats_kernel(
    const float* __restrict__ acc,
    float* __restrict__ sums,
    int n_out)
{
    int c = threadIdx.x;
    float s = 0.0f, s2 = 0.0f;
    for (int r = blockIdx.x; r < n_out; r += gridDim.x) {
        float v = acc[(size_t)r * OUT_CH + c];
        s += v;
        s2 += v * v;
    }
    atomicAdd(&sums[c], s);
    atomicAdd(&sums[OUT_CH + c], s2);
}

// ---------- launch ----------

extern "C" void kernel_launch(void* const* d_in, const int* in_sizes, int n_in,
                              void* d_out, int out_size, void* d_ws, size_t ws_size,
                              hipStream_t stream) {
    const float* feats   = (const float*)d_in[0];
    const float* W       = (const float*)d_in[1];
    const float* gamma   = (const float*)d_in[2];
    const float* beta    = (const float*)d_in[3];
    const int*   in_idx  = (const int*)d_in[4];
    const int*   out_idx = (const int*)d_in[5];
    const int*   mask    = (const int*)d_in[6];   // bool stored as int32

    const int R = in_sizes[4] / 9;
    const int n_out = out_size / OUT_CH;
    const int N_in = in_sizes[0] / IN_CH;
    float* acc = (float*)d_out;

    size_t off_inv  = 0;
    size_t sz_inv   = (size_t)n_out * 9 * sizeof(int);
    size_t off_sums = (off_inv + sz_inv + 15) & ~(size_t)15;
    size_t off_fb   = (off_sums + 1024 + 15) & ~(size_t)15;
    size_t off_wbt  = (off_fb + (size_t)(N_in + 1) * IN_CH * 2 + 15) & ~(size_t)15;
    size_t needed   = off_wbt + (size_t)9 * OUT_CH * IN_CH * 2;

    if (ws_size >= needed) {
        int*    inv  = (int*)((char*)d_ws + off_inv);
        float*  sums = (float*)((char*)d_ws + off_sums);
        ushort* fb   = (ushort*)((char*)d_ws + off_fb);
        ushort* wbt  = (ushort*)((char*)d_ws + off_wbt);

        const int invTot = n_out * 9;
        const int n4 = N_in * IN_CH / 4;
        const int invBlocks = (invTot + 255) / 256;
        const int cvtBlocks = (n4 + 16 + 255) / 256;
        const int wbtBlocks = (9 * OUT_CH * IN_CH + 255) / 256;

        prep_kernel<<<invBlocks + cvtBlocks + wbtBlocks, 256, 0, stream>>>(
            inv, invTot, N_in, sums,
            (const float4*)feats, fb, n4,
            W, wbt, invBlocks, cvtBlocks);

        dim3 gridB((R + 255) / 256, 9);
        build_inv_kernel<<<gridB, 256, 0, stream>>>(in_idx, out_idx, mask, inv, R);

        fused_out_kernel<<<(n_out + 63) / 64, 256, 0, stream>>>(
            fb, wbt, inv, acc, sums, n_out, N_in);

        int total4 = out_size / 4;
        bn_relu_kernel<<<(total4 + 255) / 256, 256, 0, stream>>>(
            (float4*)acc, sums, gamma, beta, total4, 1.0f / (float)n_out);
    } else {
        float* sums = (float*)d_ws;
        int n4 = out_size / 4;
        zero_kernel<<<(n4 + 255) / 256, 256, 0, stream>>>((float4*)acc, n4, sums);

        dim3 grid((R + 127) / 128, 9);
        scatter_gemm_kernel<<<grid, 256, 0, stream>>>(feats, W, in_idx, out_idx, mask, acc, R);

        stats_kernel<<<2048, 128, 0, stream>>>(acc, sums, n_out);

        int total4 = out_size / 4;
        bn_relu_kernel<<<(total4 + 255) / 256, 256, 0, stream>>>(
            (float4*)acc, sums, gamma, beta, total4, 1.0f / (float)n_out);
    }
}

// Round 3
// 433.252 us; speedup vs baseline: 1.7108x; 1.7108x over previous
//
#include <hip/hip_runtime.h>
#include <hip/hip_bf16.h>
#include <stdint.h>

#define IN_CH 64
#define OUT_CH 128

typedef __bf16 bf16x8 __attribute__((ext_vector_type(8)));
typedef float  f32x4  __attribute__((ext_vector_type(4)));

__device__ inline unsigned short f2bf(float f) {
    unsigned u = __float_as_uint(f);
    unsigned r = (u + 0x7fffu + ((u >> 16) & 1u)) >> 16;
    return (unsigned short)r;
}

// ---------- fast path ----------

// One prep kernel, three block-ranges:
//  [0, invBlocks)                : inv[] = zero_row; sums = 0
//  [invBlocks, invBlocks+cvtB)   : feats fp32 -> bf16 (+1 zero row)
//  [invBlocks+cvtB, ...)         : W -> wsw, bf16 in MFMA-A fragment order:
//     wsw[((k*16 + g*2 + h)*64 + lane)*8 + j] = bf16(W[k][h*32+(lane>>4)*8+j][g*16+(lane&15)])
//  so the fused kernel's W-fragment load is lane*16B fully coalesced.
__global__ void __launch_bounds__(256) prep_kernel(
    int* __restrict__ inv, int invTot, int zero_row, float* __restrict__ sums,
    const float4* __restrict__ f4, ushort* __restrict__ fb, int n4,
    const float* __restrict__ W, ushort* __restrict__ wsw,
    int invBlocks, int cvtBlocks)
{
    const int b = blockIdx.x;
    const int t = threadIdx.x;
    if (b < invBlocks) {
        int i = b * 256 + t;
        if (i < invTot) inv[i] = zero_row;
        if (b == 0) sums[t] = 0.f;
    } else if (b < invBlocks + cvtBlocks) {
        int i = (b - invBlocks) * 256 + t;
        if (i < n4 + 16) {
            ushort4 o;
            if (i < n4) {
                float4 v = f4[i];
                o.x = f2bf(v.x); o.y = f2bf(v.y); o.z = f2bf(v.z); o.w = f2bf(v.w);
            } else {
                o.x = 0; o.y = 0; o.z = 0; o.w = 0;   // zero row for absent entries
            }
            ((ushort4*)fb)[i] = o;
        }
    } else {
        int i = (b - invBlocks - cvtBlocks) * 256 + t;  // one thread = one fragment chunk
        if (i < 9 * 16 * 64) {
            int lane = i & 63;
            int gh = (i >> 6) & 15;
            int k = i >> 10;
            int half = gh & 1;
            int g = gh >> 1;
            int ch = g * 16 + (lane & 15);
            int in0 = half * 32 + (lane >> 4) * 8;
            ushort v[8];
#pragma unroll
            for (int j = 0; j < 8; ++j)
                v[j] = f2bf(W[((size_t)k * IN_CH + in0 + j) * OUT_CH + ch]);
            *(ushort4*)(wsw + (size_t)i * 8)     = make_ushort4(v[0], v[1], v[2], v[3]);
            *(ushort4*)(wsw + (size_t)i * 8 + 4) = make_ushort4(v[4], v[5], v[6], v[7]);
        }
    }
}

// Inverse rulebook, atomic-free: for fixed k the in->out map of a strided
// conv is injective, so inv[out*9+k] has exactly one writer.
__global__ void __launch_bounds__(256) build_inv_kernel(
    const int* __restrict__ in_idx,
    const int* __restrict__ out_idx,
    const int* __restrict__ mask,
    int* __restrict__ inv,
    int R)
{
    int r = blockIdx.x * 256 + threadIdx.x;
    if (r >= R) return;
    int k = blockIdx.y;
    size_t e = (size_t)k * R + r;
    if (!mask[e]) return;
    inv[(size_t)out_idx[e] * 9 + k] = in_idx[e];
}

// Fused: out[e] = sum_k W[k]^T . fb[inv[e][k]], + fused BN-stat partials.
// Wave = 32 entries (2 MFMA groups) x 128 channels. mfma(W,F): D is
// [ch][entry] -> lane holds 4 consecutive channels of one entry -> float4
// stores. W-fragments load coalesced from the pre-swizzled wsw. F-gathers
// for k+1 issue inside iteration k (depth-1 pipeline, 2 fragment sets live);
// sched_barrier(0) per iteration stops the unroller from hoisting all
// gathers (round-2 spill lesson).
__global__ void __launch_bounds__(256, 3) fused_out_kernel(
    const ushort* __restrict__ fb,    // [N_in+1][64] bf16 (last row zeros)
    const ushort* __restrict__ wsw,   // [9][16][64][8] bf16 fragment-order
    const int* __restrict__ inv,      // [n_out][9]
    float* __restrict__ out,          // [n_out][128] fp32
    float* __restrict__ sums,         // [256]
    int n_out, int zero_row)
{
    const int lane = threadIdx.x & 63;
    const int w = threadIdx.x >> 6;
    const int col = lane & 15;
    const int quad = lane >> 4;
    const int base = blockIdx.x * 128 + w * 32;
    const int eA = base + col;
    const int eB = base + 16 + col;
    const bool okA = eA < n_out;
    const bool okB = eB < n_out;

    int ivA[9], ivB[9];
    {
        const int* __restrict__ pA = inv + (size_t)(okA ? eA : 0) * 9;
        const int* __restrict__ pB = inv + (size_t)(okB ? eB : 0) * 9;
#pragma unroll
        for (int k = 0; k < 9; ++k) ivA[k] = okA ? pA[k] : zero_row;
#pragma unroll
        for (int k = 0; k < 9; ++k) ivB[k] = okB ? pB[k] : zero_row;
    }

    f32x4 accA[8], accB[8];
#pragma unroll
    for (int g = 0; g < 8; ++g) {
        accA[g] = (f32x4){0.f, 0.f, 0.f, 0.f};
        accB[g] = (f32x4){0.f, 0.f, 0.f, 0.f};
    }

    // Double-buffered F fragments (indices static after full unroll).
    bf16x8 FA0[2], FA1[2], FB0[2], FB1[2];
    {
        const ushort* __restrict__ fa = fb + (size_t)ivA[0] * IN_CH + quad * 8;
        FA0[0] = *(const bf16x8*)fa;
        FA1[0] = *(const bf16x8*)(fa + 32);
        const ushort* __restrict__ fbp = fb + (size_t)ivB[0] * IN_CH + quad * 8;
        FB0[0] = *(const bf16x8*)fbp;
        FB1[0] = *(const bf16x8*)(fbp + 32);
    }

#pragma unroll
    for (int k = 0; k < 9; ++k) {
        const int cur = k & 1;
        const int nxt = cur ^ 1;
        if (k < 8) {
            const ushort* __restrict__ fa = fb + (size_t)ivA[k + 1] * IN_CH + quad * 8;
            FA0[nxt] = *(const bf16x8*)fa;
            FA1[nxt] = *(const bf16x8*)(fa + 32);
            const ushort* __restrict__ fbp = fb + (size_t)ivB[k + 1] * IN_CH + quad * 8;
            FB0[nxt] = *(const bf16x8*)fbp;
            FB1[nxt] = *(const bf16x8*)(fbp + 32);
        }
        const ushort* __restrict__ wk = wsw + (size_t)k * (16 * 64 * 8) + lane * 8;
#pragma unroll
        for (int g = 0; g < 8; ++g) {
            bf16x8 W0 = *(const bf16x8*)(wk + (g * 2 + 0) * 512);
            bf16x8 W1 = *(const bf16x8*)(wk + (g * 2 + 1) * 512);
            accA[g] = __builtin_amdgcn_mfma_f32_16x16x32_bf16(W0, FA0[cur], accA[g], 0, 0, 0);
            accA[g] = __builtin_amdgcn_mfma_f32_16x16x32_bf16(W1, FA1[cur], accA[g], 0, 0, 0);
            accB[g] = __builtin_amdgcn_mfma_f32_16x16x32_bf16(W0, FB0[cur], accB[g], 0, 0, 0);
            accB[g] = __builtin_amdgcn_mfma_f32_16x16x32_bf16(W1, FB1[cur], accB[g], 0, 0, 0);
        }
        __builtin_amdgcn_sched_barrier(0);
    }

    // Store: lane holds channels g*16 + quad*4 + {0..3} of its entry.
    if (okA) {
        float* __restrict__ rp = out + (size_t)eA * OUT_CH + quad * 4;
#pragma unroll
        for (int g = 0; g < 8; ++g)
            *(f32x4*)(rp + g * 16) = accA[g];
    }
    if (okB) {
        float* __restrict__ rp = out + (size_t)eB * OUT_CH + quad * 4;
#pragma unroll
        for (int g = 0; g < 8; ++g)
            *(f32x4*)(rp + g * 16) = accB[g];
    }

    // BN stats: sum over entries = butterfly over the 16 col-lanes (masks
    // 1..8 stay inside a quad). Invalid entries are exact zeros.
    f32x4 ss[8], qq[8];
#pragma unroll
    for (int g = 0; g < 8; ++g) {
        ss[g] = accA[g] + accB[g];
        qq[g] = accA[g] * accA[g] + accB[g] * accB[g];
    }
#pragma unroll
    for (int m = 1; m <= 8; m <<= 1) {
#pragma unroll
        for (int g = 0; g < 8; ++g) {
#pragma unroll
            for (int j = 0; j < 4; ++j) {
                ss[g][j] += __shfl_xor(ss[g][j], m);
                qq[g][j] += __shfl_xor(qq[g][j], m);
            }
        }
    }

    __shared__ float redS[4][OUT_CH];
    __shared__ float redQ[4][OUT_CH];
    if (col == 0) {
#pragma unroll
        for (int g = 0; g < 8; ++g)
#pragma unroll
            for (int j = 0; j < 4; ++j) {
                redS[w][g * 16 + quad * 4 + j] = ss[g][j];
                redQ[w][g * 16 + quad * 4 + j] = qq[g][j];
            }
    }
    __syncthreads();
    if (threadIdx.x < OUT_CH) {
        int c = threadIdx.x;
        float a  = redS[0][c] + redS[1][c] + redS[2][c] + redS[3][c];
        float bq = redQ[0][c] + redQ[1][c] + redQ[2][c] + redQ[3][c];
        atomicAdd(&sums[c], a);
        atomicAdd(&sums[OUT_CH + c], bq);
    }
}

// y = gamma*(x-mean)*rsqrt(var+eps)+beta, relu; in-place, float4.
__global__ void __launch_bounds__(256) bn_relu_kernel(
    float4* __restrict__ out,
    const float* __restrict__ sums,
    const float* __restrict__ gamma,
    const float* __restrict__ beta,
    int total4, float inv_n)
{
    int idx = blockIdx.x * 256 + threadIdx.x;
    if (idx >= total4) return;
    int c0 = (idx & 31) * 4;
    float4 v = out[idx];
    float r[4] = {v.x, v.y, v.z, v.w};
#pragma unroll
    for (int j = 0; j < 4; ++j) {
        int c = c0 + j;
        float mean = sums[c] * inv_n;
        float var = sums[OUT_CH + c] * inv_n - mean * mean;
        float scale = gamma[c] * rsqrtf(var + 1e-5f);
        float y = (r[j] - mean) * scale + beta[c];
        r[j] = fmaxf(y, 0.0f);
    }
    out[idx] = make_float4(r[0], r[1], r[2], r[3]);
}

// ---------- fallback (atomic scatter) if ws too small ----------

__global__ void __launch_bounds__(256) zero_kernel(float4* __restrict__ out, int n4,
                                                   float* __restrict__ sums) {
    int idx = blockIdx.x * 256 + threadIdx.x;
    if (idx < n4) out[idx] = make_float4(0.f, 0.f, 0.f, 0.f);
    if (blockIdx.x == 0 && threadIdx.x < 2 * OUT_CH) sums[threadIdx.x] = 0.f;
}

__global__ void __launch_bounds__(256) scatter_gemm_kernel(
    const float* __restrict__ feats,
    const float* __restrict__ W,
    const int* __restrict__ in_idx,
    const int* __restrict__ out_idx,
    const int* __restrict__ mask,
    float* __restrict__ acc,
    int R)
{
    const int lane = threadIdx.x & 63;
    const int waveId = threadIdx.x >> 6;
    const int half = waveId & 1;
    const int pair = waveId >> 1;
    const int k = blockIdx.y;
    const int c = half * 64 + lane;

    float wreg[IN_CH];
    const float* __restrict__ wp = W + (size_t)k * IN_CH * OUT_CH + c;
#pragma unroll
    for (int i = 0; i < IN_CH; ++i) wreg[i] = wp[i * OUT_CH];

    const int r0 = blockIdx.x * 128;
    const int rEnd = min(r0 + 128, R);
    const int* __restrict__ maskK = mask + (size_t)k * R;
    const int* __restrict__ inK = in_idx + (size_t)k * R;
    const int* __restrict__ outK = out_idx + (size_t)k * R;

    for (int r = r0 + pair; r < rEnd; r += 2) {
        if (!__builtin_amdgcn_readfirstlane(maskK[r])) continue;
        int in = __builtin_amdgcn_readfirstlane(inK[r]);
        int out = __builtin_amdgcn_readfirstlane(outK[r]);
        const float* __restrict__ f = feats + (size_t)in * IN_CH;
        float s = 0.f, s1 = 0.f;
#pragma unroll
        for (int i = 0; i < IN_CH; i += 2) {
            s = fmaf(wreg[i], f[i], s);
            s1 = fmaf(wreg[i + 1], f[i + 1], s1);
        }
        atomicAdd(acc + (size_t)out * OUT_CH + c, s + s1);
    }
}

__global__ void __launch_bounds__(128) stats_kernel(
    const float* __restrict__ acc,
    float* __restrict__ sums,
    int n_out)
{
    int c = threadIdx.x;
    float s = 0.0f, s2 = 0.0f;
    for (int r = blockIdx.x; r < n_out; r += gridDim.x) {
        float v = acc[(size_t)r * OUT_CH + c];
        s += v;
        s2 += v * v;
    }
    atomicAdd(&sums[c], s);
    atomicAdd(&sums[OUT_CH + c], s2);
}

// ---------- launch ----------

extern "C" void kernel_launch(void* const* d_in, const int* in_sizes, int n_in,
                              void* d_out, int out_size, void* d_ws, size_t ws_size,
                              hipStream_t stream) {
    const float* feats   = (const float*)d_in[0];
    const float* W       = (const float*)d_in[1];
    const float* gamma   = (const float*)d_in[2];
    const float* beta    = (const float*)d_in[3];
    const int*   in_idx  = (const int*)d_in[4];
    const int*   out_idx = (const int*)d_in[5];
    const int*   mask    = (const int*)d_in[6];   // bool stored as int32

    const int R = in_sizes[4] / 9;
    const int n_out = out_size / OUT_CH;
    const int N_in = in_sizes[0] / IN_CH;
    float* acc = (float*)d_out;

    size_t off_inv  = 0;
    size_t sz_inv   = (size_t)n_out * 9 * sizeof(int);
    size_t off_sums = (off_inv + sz_inv + 15) & ~(size_t)15;
    size_t off_fb   = (off_sums + 1024 + 15) & ~(size_t)15;
    size_t off_wsw  = (off_fb + (size_t)(N_in + 1) * IN_CH * 2 + 15) & ~(size_t)15;
    size_t needed   = off_wsw + (size_t)9 * OUT_CH * IN_CH * 2;

    if (ws_size >= needed) {
        int*    inv  = (int*)((char*)d_ws + off_inv);
        float*  sums = (float*)((char*)d_ws + off_sums);
        ushort* fb   = (ushort*)((char*)d_ws + off_fb);
        ushort* wsw  = (ushort*)((char*)d_ws + off_wsw);

        const int invTot = n_out * 9;
        const int n4 = N_in * IN_CH / 4;
        const int invBlocks = (invTot + 255) / 256;
        const int cvtBlocks = (n4 + 16 + 255) / 256;
        const int wswBlocks = (9 * 16 * 64 + 255) / 256;

        prep_kernel<<<invBlocks + cvtBlocks + wswBlocks, 256, 0, stream>>>(
            inv, invTot, N_in, sums,
            (const float4*)feats, fb, n4,
            W, wsw, invBlocks, cvtBlocks);

        dim3 gridB((R + 255) / 256, 9);
        build_inv_kernel<<<gridB, 256, 0, stream>>>(in_idx, out_idx, mask, inv, R);

        fused_out_kernel<<<(n_out + 127) / 128, 256, 0, stream>>>(
            fb, wsw, inv, acc, sums, n_out, N_in);

        int total4 = out_size / 4;
        bn_relu_kernel<<<(total4 + 255) / 256, 256, 0, stream>>>(
            (float4*)acc, sums, gamma, beta, total4, 1.0f / (float)n_out);
    } else {
        float* sums = (float*)d_ws;
        int n4 = out_size / 4;
        zero_kernel<<<(n4 + 255) / 256, 256, 0, stream>>>((float4*)acc, n4, sums);

        dim3 grid((R + 127) / 128, 9);
        scatter_gemm_kernel<<<grid, 256, 0, stream>>>(feats, W, in_idx, out_idx, mask, acc, R);

        stats_kernel<<<2048, 128, 0, stream>>>(acc, sums, n_out);

        int total4 = out_size / 4;
        bn_relu_kernel<<<(total4 + 255) / 256, 256, 0, stream>>>(
            (float4*)acc, sums, gamma, beta, total4, 1.0f / (float)n_out);
    }
}

// Round 4
// 399.157 us; speedup vs baseline: 1.8570x; 1.0854x over previous
//
#include <hip/hip_runtime.h>
#include <hip/hip_bf16.h>
#include <stdint.h>

#define IN_CH 64
#define OUT_CH 128

typedef __bf16 bf16x8 __attribute__((ext_vector_type(8)));
typedef float  f32x4  __attribute__((ext_vector_type(4)));

__device__ inline unsigned short f2bf(float f) {
    unsigned u = __float_as_uint(f);
    unsigned r = (u + 0x7fffu + ((u >> 16) & 1u)) >> 16;
    return (unsigned short)r;
}

// ---------- fast path ----------

// One prep kernel, three block-ranges:
//  [0, invBlocks)                : inv[] = zero_row; sums = 0
//  [invBlocks, invBlocks+cvtB)   : feats fp32 -> bf16 (+1 zero row)
//  [invBlocks+cvtB, ...)         : W -> wsw, bf16 in MFMA-A fragment order:
//     wsw[((k*16 + g*2 + h)*64 + lane)*8 + j] = bf16(W[k][h*32+(lane>>4)*8+j][g*16+(lane&15)])
__global__ void __launch_bounds__(256) prep_kernel(
    int* __restrict__ inv, int invTot, int zero_row, float* __restrict__ sums,
    const float4* __restrict__ f4, ushort* __restrict__ fb, int n4,
    const float* __restrict__ W, ushort* __restrict__ wsw,
    int invBlocks, int cvtBlocks)
{
    const int b = blockIdx.x;
    const int t = threadIdx.x;
    if (b < invBlocks) {
        int i = b * 256 + t;
        if (i < invTot) inv[i] = zero_row;
        if (b == 0) sums[t] = 0.f;
    } else if (b < invBlocks + cvtBlocks) {
        int i = (b - invBlocks) * 256 + t;
        if (i < n4 + 16) {
            ushort4 o;
            if (i < n4) {
                float4 v = f4[i];
                o.x = f2bf(v.x); o.y = f2bf(v.y); o.z = f2bf(v.z); o.w = f2bf(v.w);
            } else {
                o.x = 0; o.y = 0; o.z = 0; o.w = 0;   // zero row for absent entries
            }
            ((ushort4*)fb)[i] = o;
        }
    } else {
        int i = (b - invBlocks - cvtBlocks) * 256 + t;  // one thread = one fragment chunk
        if (i < 9 * 16 * 64) {
            int lane = i & 63;
            int gh = (i >> 6) & 15;
            int k = i >> 10;
            int half = gh & 1;
            int g = gh >> 1;
            int ch = g * 16 + (lane & 15);
            int in0 = half * 32 + (lane >> 4) * 8;
            ushort v[8];
#pragma unroll
            for (int j = 0; j < 8; ++j)
                v[j] = f2bf(W[((size_t)k * IN_CH + in0 + j) * OUT_CH + ch]);
            *(ushort4*)(wsw + (size_t)i * 8)     = make_ushort4(v[0], v[1], v[2], v[3]);
            *(ushort4*)(wsw + (size_t)i * 8 + 4) = make_ushort4(v[4], v[5], v[6], v[7]);
        }
    }
}

// Inverse rulebook, atomic-free: for fixed k the in->out map of a strided
// conv is injective, so inv[out*9+k] has exactly one writer.
__global__ void __launch_bounds__(256) build_inv_kernel(
    const int* __restrict__ in_idx,
    const int* __restrict__ out_idx,
    const int* __restrict__ mask,
    int* __restrict__ inv,
    int R)
{
    int r = blockIdx.x * 256 + threadIdx.x;
    if (r >= R) return;
    int k = blockIdx.y;
    size_t e = (size_t)k * R + r;
    if (!mask[e]) return;
    inv[(size_t)out_idx[e] * 9 + k] = in_idx[e];
}

// Fused: out[e] = sum_k W[k]^T . fb[inv[e][k]], + fused BN-stat partials.
// Wave = 32 entries x 128 channels. W tiles (16KB per k) are double-buffered
// in LDS via reg-staging so the MFMA waits on W are lgkmcnt-only: the vmcnt
// queue holds ONLY {stage(k+1), F(k+1)} and every wait on it is counted
// (stage issued before F => waiting for stage leaves F in flight). Raw
// s_barrier (not __syncthreads) avoids the compiler's vmcnt(0) drain.
__global__ void __launch_bounds__(256, 3) fused_out_kernel(
    const ushort* __restrict__ fb,    // [N_in+1][64] bf16 (last row zeros)
    const ushort* __restrict__ wsw,   // [9][16][64][8] bf16 fragment-order
    const int* __restrict__ inv,      // [n_out][9]
    float* __restrict__ out,          // [n_out][128] fp32
    float* __restrict__ sums,         // [256]
    int n_out, int zero_row)
{
    __shared__ ushort ldsW[2][8192];  // 2 x 16KB W tiles
    __shared__ float redS[4][OUT_CH];
    __shared__ float redQ[4][OUT_CH];

    const int lane = threadIdx.x & 63;
    const int w = threadIdx.x >> 6;
    const int col = lane & 15;
    const int quad = lane >> 4;
    const int base = blockIdx.x * 128 + w * 32;
    const int eA = base + col;
    const int eB = base + 16 + col;
    const bool okA = eA < n_out;
    const bool okB = eB < n_out;

    int ivA[9], ivB[9];
    {
        const int* __restrict__ pA = inv + (size_t)(okA ? eA : 0) * 9;
        const int* __restrict__ pB = inv + (size_t)(okB ? eB : 0) * 9;
#pragma unroll
        for (int k = 0; k < 9; ++k) ivA[k] = okA ? pA[k] : zero_row;
#pragma unroll
        for (int k = 0; k < 9; ++k) ivB[k] = okB ? pB[k] : zero_row;
    }

    // This wave's staging quarter of a 16KB tile: bytes [w*4K, w*4K+4K).
    const int soff = w * 4096 + lane * 16;

    f32x4 accA[8], accB[8];
#pragma unroll
    for (int g = 0; g < 8; ++g) {
        accA[g] = (f32x4){0.f, 0.f, 0.f, 0.f};
        accB[g] = (f32x4){0.f, 0.f, 0.f, 0.f};
    }

    bf16x8 FA0[2], FA1[2], FB0[2], FB1[2];

    // ---- prologue: stage W(0) -> lds[0], gather F(0) ----
    {
        float4 vw[4];
        const char* src = (const char*)wsw + soff;
#pragma unroll
        for (int j = 0; j < 4; ++j)
            vw[j] = *(const float4*)(src + j * 1024);
        const ushort* fa = fb + (size_t)ivA[0] * IN_CH + quad * 8;
        FA0[0] = *(const bf16x8*)fa;
        FA1[0] = *(const bf16x8*)(fa + 32);
        const ushort* fbp = fb + (size_t)ivB[0] * IN_CH + quad * 8;
        FB0[0] = *(const bf16x8*)fbp;
        FB1[0] = *(const bf16x8*)(fbp + 32);
        char* dst = (char*)&ldsW[0][0] + soff;
#pragma unroll
        for (int j = 0; j < 4; ++j)
            *(float4*)(dst + j * 1024) = vw[j];   // waits vmcnt(4): F(0) stays in flight
        asm volatile("s_waitcnt lgkmcnt(0)" ::: "memory");
        __builtin_amdgcn_s_barrier();
        __builtin_amdgcn_sched_barrier(0);
    }

#pragma unroll
    for (int k = 0; k < 9; ++k) {
        const int cur = k & 1;
        const int nxt = cur ^ 1;

        // 1. issue stage loads for W(k+1) (oldest in vmcnt queue)
        float4 vw[4];
        if (k < 8) {
            const char* src = (const char*)wsw + (size_t)(k + 1) * 16384 + soff;
#pragma unroll
            for (int j = 0; j < 4; ++j)
                vw[j] = *(const float4*)(src + j * 1024);
            // 2. issue F(k+1) gathers (youngest; never drained by stage waits)
            const ushort* fa = fb + (size_t)ivA[k + 1] * IN_CH + quad * 8;
            FA0[nxt] = *(const bf16x8*)fa;
            FA1[nxt] = *(const bf16x8*)(fa + 32);
            const ushort* fbp = fb + (size_t)ivB[k + 1] * IN_CH + quad * 8;
            FB0[nxt] = *(const bf16x8*)fbp;
            FB1[nxt] = *(const bf16x8*)(fbp + 32);
        }

        // 3. compute: W frags from lds[cur] (lgkm waits), F(k) already landed
        const ushort* wl = &ldsW[cur][lane * 8];
#pragma unroll
        for (int g = 0; g < 8; ++g) {
            bf16x8 W0 = *(const bf16x8*)(wl + (g * 2 + 0) * 512);
            bf16x8 W1 = *(const bf16x8*)(wl + (g * 2 + 1) * 512);
            accA[g] = __builtin_amdgcn_mfma_f32_16x16x32_bf16(W0, FA0[cur], accA[g], 0, 0, 0);
            accA[g] = __builtin_amdgcn_mfma_f32_16x16x32_bf16(W1, FA1[cur], accA[g], 0, 0, 0);
            accB[g] = __builtin_amdgcn_mfma_f32_16x16x32_bf16(W0, FB0[cur], accB[g], 0, 0, 0);
            accB[g] = __builtin_amdgcn_mfma_f32_16x16x32_bf16(W1, FB1[cur], accB[g], 0, 0, 0);
        }

        // 4. commit stage to lds[nxt]; counted vmcnt leaves F(k+1) in flight
        if (k < 8) {
            char* dst = (char*)&ldsW[nxt][0] + soff;
#pragma unroll
            for (int j = 0; j < 4; ++j)
                *(float4*)(dst + j * 1024) = vw[j];
            asm volatile("s_waitcnt lgkmcnt(0)" ::: "memory");
            __builtin_amdgcn_s_barrier();
            __builtin_amdgcn_sched_barrier(0);
        }
    }

    // Store: lane holds channels g*16 + quad*4 + {0..3} of its entry.
    if (okA) {
        float* __restrict__ rp = out + (size_t)eA * OUT_CH + quad * 4;
#pragma unroll
        for (int g = 0; g < 8; ++g)
            *(f32x4*)(rp + g * 16) = accA[g];
    }
    if (okB) {
        float* __restrict__ rp = out + (size_t)eB * OUT_CH + quad * 4;
#pragma unroll
        for (int g = 0; g < 8; ++g)
            *(f32x4*)(rp + g * 16) = accB[g];
    }

    // BN stats: sum over entries = butterfly over the 16 col-lanes (masks
    // 1..8 stay inside a quad). Invalid entries are exact zeros.
    f32x4 ss[8], qq[8];
#pragma unroll
    for (int g = 0; g < 8; ++g) {
        ss[g] = accA[g] + accB[g];
        qq[g] = accA[g] * accA[g] + accB[g] * accB[g];
    }
#pragma unroll
    for (int m = 1; m <= 8; m <<= 1) {
#pragma unroll
        for (int g = 0; g < 8; ++g) {
#pragma unroll
            for (int j = 0; j < 4; ++j) {
                ss[g][j] += __shfl_xor(ss[g][j], m);
                qq[g][j] += __shfl_xor(qq[g][j], m);
            }
        }
    }

    if (col == 0) {
#pragma unroll
        for (int g = 0; g < 8; ++g)
#pragma unroll
            for (int j = 0; j < 4; ++j) {
                redS[w][g * 16 + quad * 4 + j] = ss[g][j];
                redQ[w][g * 16 + quad * 4 + j] = qq[g][j];
            }
    }
    __syncthreads();
    if (threadIdx.x < OUT_CH) {
        int c = threadIdx.x;
        float a  = redS[0][c] + redS[1][c] + redS[2][c] + redS[3][c];
        float bq = redQ[0][c] + redQ[1][c] + redQ[2][c] + redQ[3][c];
        atomicAdd(&sums[c], a);
        atomicAdd(&sums[OUT_CH + c], bq);
    }
}

// y = gamma*(x-mean)*rsqrt(var+eps)+beta, relu; in-place, float4.
__global__ void __launch_bounds__(256) bn_relu_kernel(
    float4* __restrict__ out,
    const float* __restrict__ sums,
    const float* __restrict__ gamma,
    const float* __restrict__ beta,
    int total4, float inv_n)
{
    int idx = blockIdx.x * 256 + threadIdx.x;
    if (idx >= total4) return;
    int c0 = (idx & 31) * 4;
    float4 v = out[idx];
    float r[4] = {v.x, v.y, v.z, v.w};
#pragma unroll
    for (int j = 0; j < 4; ++j) {
        int c = c0 + j;
        float mean = sums[c] * inv_n;
        float var = sums[OUT_CH + c] * inv_n - mean * mean;
        float scale = gamma[c] * rsqrtf(var + 1e-5f);
        float y = (r[j] - mean) * scale + beta[c];
        r[j] = fmaxf(y, 0.0f);
    }
    out[idx] = make_float4(r[0], r[1], r[2], r[3]);
}

// ---------- fallback (atomic scatter) if ws too small ----------

__global__ void __launch_bounds__(256) zero_kernel(float4* __restrict__ out, int n4,
                                                   float* __restrict__ sums) {
    int idx = blockIdx.x * 256 + threadIdx.x;
    if (idx < n4) out[idx] = make_float4(0.f, 0.f, 0.f, 0.f);
    if (blockIdx.x == 0 && threadIdx.x < 2 * OUT_CH) sums[threadIdx.x] = 0.f;
}

__global__ void __launch_bounds__(256) scatter_gemm_kernel(
    const float* __restrict__ feats,
    const float* __restrict__ W,
    const int* __restrict__ in_idx,
    const int* __restrict__ out_idx,
    const int* __restrict__ mask,
    float* __restrict__ acc,
    int R)
{
    const int lane = threadIdx.x & 63;
    const int waveId = threadIdx.x >> 6;
    const int half = waveId & 1;
    const int pair = waveId >> 1;
    const int k = blockIdx.y;
    const int c = half * 64 + lane;

    float wreg[IN_CH];
    const float* __restrict__ wp = W + (size_t)k * IN_CH * OUT_CH + c;
#pragma unroll
    for (int i = 0; i < IN_CH; ++i) wreg[i] = wp[i * OUT_CH];

    const int r0 = blockIdx.x * 128;
    const int rEnd = min(r0 + 128, R);
    const int* __restrict__ maskK = mask + (size_t)k * R;
    const int* __restrict__ inK = in_idx + (size_t)k * R;
    const int* __restrict__ outK = out_idx + (size_t)k * R;

    for (int r = r0 + pair; r < rEnd; r += 2) {
        if (!__builtin_amdgcn_readfirstlane(maskK[r])) continue;
        int in = __builtin_amdgcn_readfirstlane(inK[r]);
        int out = __builtin_amdgcn_readfirstlane(outK[r]);
        const float* __restrict__ f = feats + (size_t)in * IN_CH;
        float s = 0.f, s1 = 0.f;
#pragma unroll
        for (int i = 0; i < IN_CH; i += 2) {
            s = fmaf(wreg[i], f[i], s);
            s1 = fmaf(wreg[i + 1], f[i + 1], s1);
        }
        atomicAdd(acc + (size_t)out * OUT_CH + c, s + s1);
    }
}

__global__ void __launch_bounds__(128) stats_kernel(
    const float* __restrict__ acc,
    float* __restrict__ sums,
    int n_out)
{
    int c = threadIdx.x;
    float s = 0.0f, s2 = 0.0f;
    for (int r = blockIdx.x; r < n_out; r += gridDim.x) {
        float v = acc[(size_t)r * OUT_CH + c];
        s += v;
        s2 += v * v;
    }
    atomicAdd(&sums[c], s);
    atomicAdd(&sums[OUT_CH + c], s2);
}

// ---------- launch ----------

extern "C" void kernel_launch(void* const* d_in, const int* in_sizes, int n_in,
                              void* d_out, int out_size, void* d_ws, size_t ws_size,
                              hipStream_t stream) {
    const float* feats   = (const float*)d_in[0];
    const float* W       = (const float*)d_in[1];
    const float* gamma   = (const float*)d_in[2];
    const float* beta    = (const float*)d_in[3];
    const int*   in_idx  = (const int*)d_in[4];
    const int*   out_idx = (const int*)d_in[5];
    const int*   mask    = (const int*)d_in[6];   // bool stored as int32

    const int R = in_sizes[4] / 9;
    const int n_out = out_size / OUT_CH;
    const int N_in = in_sizes[0] / IN_CH;
    float* acc = (float*)d_out;

    size_t off_inv  = 0;
    size_t sz_inv   = (size_t)n_out * 9 * sizeof(int);
    size_t off_sums = (off_inv + sz_inv + 15) & ~(size_t)15;
    size_t off_fb   = (off_sums + 1024 + 15) & ~(size_t)15;
    size_t off_wsw  = (off_fb + (size_t)(N_in + 1) * IN_CH * 2 + 15) & ~(size_t)15;
    size_t needed   = off_wsw + (size_t)9 * OUT_CH * IN_CH * 2;

    if (ws_size >= needed) {
        int*    inv  = (int*)((char*)d_ws + off_inv);
        float*  sums = (float*)((char*)d_ws + off_sums);
        ushort* fb   = (ushort*)((char*)d_ws + off_fb);
        ushort* wsw  = (ushort*)((char*)d_ws + off_wsw);

        const int invTot = n_out * 9;
        const int n4 = N_in * IN_CH / 4;
        const int invBlocks = (invTot + 255) / 256;
        const int cvtBlocks = (n4 + 16 + 255) / 256;
        const int wswBlocks = (9 * 16 * 64 + 255) / 256;

        prep_kernel<<<invBlocks + cvtBlocks + wswBlocks, 256, 0, stream>>>(
            inv, invTot, N_in, sums,
            (const float4*)feats, fb, n4,
            W, wsw, invBlocks, cvtBlocks);

        dim3 gridB((R + 255) / 256, 9);
        build_inv_kernel<<<gridB, 256, 0, stream>>>(in_idx, out_idx, mask, inv, R);

        fused_out_kernel<<<(n_out + 127) / 128, 256, 0, stream>>>(
            fb, wsw, inv, acc, sums, n_out, N_in);

        int total4 = out_size / 4;
        bn_relu_kernel<<<(total4 + 255) / 256, 256, 0, stream>>>(
            (float4*)acc, sums, gamma, beta, total4, 1.0f / (float)n_out);
    } else {
        float* sums = (float*)d_ws;
        int n4 = out_size / 4;
        zero_kernel<<<(n4 + 255) / 256, 256, 0, stream>>>((float4*)acc, n4, sums);

        dim3 grid((R + 127) / 128, 9);
        scatter_gemm_kernel<<<grid, 256, 0, stream>>>(feats, W, in_idx, out_idx, mask, acc, R);

        stats_kernel<<<2048, 128, 0, stream>>>(acc, sums, n_out);

        int total4 = out_size / 4;
        bn_relu_kernel<<<(total4 + 255) / 256, 256, 0, stream>>>(
            (float4*)acc, sums, gamma, beta, total4, 1.0f / (float)n_out);
    }
}